// Round 5
// baseline (3260.341 us; speedup 1.0000x reference)
//
#include <hip/hip_runtime.h>
#include <hip/hip_bf16.h>

#define N_NODES 100000
#define N_EDGES 3200000
#define F_IN    128
#define H1F     64
#define H2F     32
#define NCLS    32

static __device__ __forceinline__ float b2f(__hip_bfloat16 v) {
    return __bfloat162float(v);
}

// dtype-dual load: isbf ? bf16[i] : f32[i]
static __device__ __forceinline__ float ld(const void* p, size_t i, int isbf) {
    return isbf ? b2f(((const __hip_bfloat16*)p)[i]) : ((const float*)p)[i];
}

// flags[0] = edge_index is int64
// flags[1] = float tensors are bf16-packed (else float32)

// ---------------- runtime dtype detection (single thread, ~512 loads) ----------------
__global__ void k_detect(const void* xbuf, const void* eibuf, int* flags) {
    if (threadIdx.x != 0 || blockIdx.x != 0) return;

    // edge dtype: int64 => odd 32-bit words (high halves) are ~all zero
    const unsigned* ew = (const unsigned*)eibuf;
    int z = 0;
    for (int k = 0; k < 256; ++k) z += (ew[2 * k + 1] == 0u) ? 1 : 0;
    flags[0] = (z >= 200) ? 1 : 0;

    // float dtype: decode LOW 16 bits of each word as bf16.
    // bf16-packed N(0,1): low half is a real element -> |v| in [1e-4,20] ~always.
    // f32 data: low half is mantissa bits -> random exponent -> in-range ~7%.
    const unsigned* xw = (const unsigned*)xbuf;
    int inr = 0;
    for (int k = 0; k < 256; ++k) {
        unsigned short lo = (unsigned short)(xw[k] & 0xFFFFu);
        unsigned fb = ((unsigned)lo) << 16;
        float v = __uint_as_float(fb);
        float a = fabsf(v);
        inr += (a >= 1e-4f && a <= 20.0f) ? 1 : 0;
    }
    flags[1] = (inr >= 160) ? 1 : 0;
}

// ---------------- degree / norm ----------------
__global__ void k_zero_deg(int* __restrict__ deg) {
    int i = blockIdx.x * blockDim.x + threadIdx.x;
    if (i < N_NODES) deg[i] = 0;
}

__global__ void k_count_deg(const int* __restrict__ ei, int* __restrict__ deg,
                            const int* __restrict__ flags) {
    int e = blockIdx.x * blockDim.x + threadIdx.x;
    if (e >= N_EDGES) return;
    int d = flags[0] ? ei[2 * (N_EDGES + e)] : ei[N_EDGES + e];   // dst = edge_index[1]
    if ((unsigned)d < N_NODES) atomicAdd(&deg[d], 1);
}

__global__ void k_dinv(const int* __restrict__ deg, float* __restrict__ dinv) {
    int i = blockIdx.x * blockDim.x + threadIdx.x;
    if (i < N_NODES) dinv[i] = rsqrtf((float)deg[i] + 1.0f);  // +1 self-loop
}

// ---------------- GEMM1: h1 = x @ W1   [N,128]@[128,64] ----------------
// one wave per node; lane = output feature (64)
__global__ void k_gemm1(const void* __restrict__ x, const void* __restrict__ W1,
                        float* __restrict__ h1, const int* __restrict__ flags) {
    int wid  = (blockIdx.x * blockDim.x + threadIdx.x) >> 6;   // node
    int lane = threadIdx.x & 63;
    if (wid >= N_NODES) return;
    int isbf = flags[1];
    size_t xoff = (size_t)wid * F_IN;
    float acc = 0.f;
#pragma unroll
    for (int k = 0; k < F_IN; ++k) {
        acc += ld(x, xoff + k, isbf) * ld(W1, (size_t)k * H1F + lane, isbf);
    }
    h1[(size_t)wid * H1F + lane] = acc;
}

// ---------------- aggregation layer 1 (64 feats) ----------------
// self-loop term fully initializes agg1 (overwrites ws poison)
__global__ void k_self1(const float* __restrict__ h1, const float* __restrict__ dinv,
                        float* __restrict__ agg1) {
    int i = blockIdx.x * blockDim.x + threadIdx.x;  // over N*64
    if (i < N_NODES * H1F) {
        int node = i >> 6;
        float d = dinv[node];
        agg1[i] = h1[i] * d * d;
    }
}

// one wave per edge, lane = feature
__global__ void k_edge1(const int* __restrict__ ei, const float* __restrict__ h1,
                        const float* __restrict__ dinv, float* __restrict__ agg1,
                        const int* __restrict__ flags) {
    int t    = blockIdx.x * blockDim.x + threadIdx.x;
    int e    = t >> 6;
    int lane = threadIdx.x & 63;
    if (e >= N_EDGES) return;
    int s, d;
    if (flags[0]) { s = ei[2 * e]; d = ei[2 * (N_EDGES + e)]; }
    else          { s = ei[e];     d = ei[N_EDGES + e];       }
    if ((unsigned)s >= N_NODES || (unsigned)d >= N_NODES) return;
    float c = dinv[s] * dinv[d];
    float v = h1[(size_t)s * H1F + lane] * c;
    atomicAdd(&agg1[(size_t)d * H1F + lane], v);
}

// ---------------- bias+ReLU fused with GEMM2: h2 = relu(agg1+b1) @ W2 ----------------
// half-wave (32 lanes) per node
__global__ void k_gemm2(const float* __restrict__ agg1, const void* __restrict__ b1,
                        const void* __restrict__ W2, float* __restrict__ h2,
                        const int* __restrict__ flags) {
    int tid  = blockIdx.x * blockDim.x + threadIdx.x;
    int node = tid >> 5;
    int f    = threadIdx.x & 31;
    if (node >= N_NODES) return;
    int isbf = flags[1];
    const float* ar = agg1 + (size_t)node * H1F;
    float acc = 0.f;
#pragma unroll
    for (int k = 0; k < H1F; ++k) {
        float xv = fmaxf(ar[k] + ld(b1, k, isbf), 0.f);
        acc += xv * ld(W2, (size_t)k * H2F + f, isbf);
    }
    h2[(size_t)node * H2F + f] = acc;
}

// ---------------- aggregation layer 2 (32 feats) ----------------
__global__ void k_self2(const float* __restrict__ h2, const float* __restrict__ dinv,
                        float* __restrict__ agg2) {
    int i = blockIdx.x * blockDim.x + threadIdx.x;  // over N*32
    if (i < N_NODES * H2F) {
        int node = i >> 5;
        float d = dinv[node];
        agg2[i] = h2[i] * d * d;
    }
}

__global__ void k_edge2(const int* __restrict__ ei, const float* __restrict__ h2,
                        const float* __restrict__ dinv, float* __restrict__ agg2,
                        const int* __restrict__ flags) {
    int t = blockIdx.x * blockDim.x + threadIdx.x;
    int e = t >> 5;
    int f = threadIdx.x & 31;
    if (e >= N_EDGES) return;
    int s, d;
    if (flags[0]) { s = ei[2 * e]; d = ei[2 * (N_EDGES + e)]; }
    else          { s = ei[e];     d = ei[N_EDGES + e];       }
    if ((unsigned)s >= N_NODES || (unsigned)d >= N_NODES) return;
    float c = dinv[s] * dinv[d];
    float v = h2[(size_t)s * H2F + f] * c;
    atomicAdd(&agg2[(size_t)d * H2F + f], v);
}

// ---------------- final: out = relu((agg2+b2) @ Wf + bf) @ Wo + bo ----------------
// output dtype follows the detected input dtype policy
__global__ void GCN_51737176048479_kernel(const float* __restrict__ agg2,
                                          const void* __restrict__ b2v,
                                          const void* __restrict__ Wf,
                                          const void* __restrict__ bfv,
                                          const void* __restrict__ Wo,
                                          const void* __restrict__ bo,
                                          void* __restrict__ out,
                                          const int* __restrict__ flags) {
    int tid  = blockIdx.x * blockDim.x + threadIdx.x;
    int node = tid >> 5;
    int f    = threadIdx.x & 31;
    if (node >= N_NODES) return;
    int isbf = flags[1];
    const float* ar = agg2 + (size_t)node * H2F;
    float acc1 = 0.f;
#pragma unroll
    for (int k = 0; k < H2F; ++k) {
        float xv = ar[k] + ld(b2v, k, isbf);
        acc1 += xv * ld(Wf, (size_t)k * H2F + f, isbf);
    }
    float u = fmaxf(acc1 + ld(bfv, f, isbf), 0.f);
    float acc2 = 0.f;
#pragma unroll
    for (int k = 0; k < H2F; ++k) {
        float uk = __shfl(u, k, 32);            // hidden[k] within this half-wave
        acc2 += uk * ld(Wo, (size_t)k * NCLS + f, isbf);
    }
    float r = acc2 + ld(bo, f, isbf);
    size_t oi = (size_t)node * NCLS + f;
    if (isbf) ((__hip_bfloat16*)out)[oi] = __float2bfloat16(r);
    else      ((float*)out)[oi] = r;
}

extern "C" void kernel_launch(void* const* d_in, const int* in_sizes, int n_in,
                              void* d_out, int out_size, void* d_ws, size_t ws_size,
                              hipStream_t stream) {
    // documented dict order
    const void* x  = d_in[0];
    const int*  ei = (const int*)d_in[1];
    const void* W1 = d_in[2];
    const void* b1 = d_in[3];
    const void* W2 = d_in[4];
    const void* b2 = d_in[5];
    const void* Wf = d_in[6];
    const void* bf = d_in[7];
    const void* Wo = d_in[8];
    const void* bo = d_in[9];

    // workspace layout (bytes), ~54 MB total with region reuse:
    //   deg @0 (400KB), flags @512KB, dinv @1MB (400KB)
    //   bufA @2MB  (25.6MB): h1, later h2 (12.8MB)
    //   bufB @28MB (25.6MB): agg1, later agg2 (12.8MB)
    char* ws = (char*)d_ws;
    int*   deg   = (int*)  (ws + 0);
    int*   flags = (int*)  (ws + (512u << 10));
    float* dinv  = (float*)(ws + (1u << 20));
    float* h1    = (float*)(ws + (2u << 20));
    float* agg1  = (float*)(ws + (28u << 20));
    float* h2    = h1;     // bufA reuse: h1 dead after agg1 is built
    float* agg2  = agg1;   // bufB reuse: agg1 consumed by k_gemm2

    const int B = 256;

    k_detect<<<1, 64, 0, stream>>>(x, ei, flags);
    k_zero_deg<<<(N_NODES + B - 1) / B, B, 0, stream>>>(deg);
    k_count_deg<<<(N_EDGES + B - 1) / B, B, 0, stream>>>(ei, deg, flags);
    k_dinv<<<(N_NODES + B - 1) / B, B, 0, stream>>>(deg, dinv);

    // layer 1
    k_gemm1<<<(N_NODES * 64 + B - 1) / B, B, 0, stream>>>(x, W1, h1, flags);
    k_self1<<<(N_NODES * H1F + B - 1) / B, B, 0, stream>>>(h1, dinv, agg1);
    {
        long long threads = (long long)N_EDGES * 64;
        k_edge1<<<(unsigned)((threads + B - 1) / B), B, 0, stream>>>(ei, h1, dinv, agg1, flags);
    }

    // layer 2 (h2 overwrites bufA; agg1 consumed here)
    k_gemm2<<<(N_NODES * 32 + B - 1) / B, B, 0, stream>>>(agg1, b1, W2, h2, flags);
    k_self2<<<(N_NODES * H2F + B - 1) / B, B, 0, stream>>>(h2, dinv, agg2);
    {
        long long threads = (long long)N_EDGES * 32;
        k_edge2<<<(unsigned)((threads + B - 1) / B), B, 0, stream>>>(ei, h2, dinv, agg2, flags);
    }

    // final MLP
    GCN_51737176048479_kernel<<<(N_NODES * 32 + B - 1) / B, B, 0, stream>>>(
        agg2, b2, Wf, bf, Wo, bo, d_out, flags);
}

// Round 6
// 1323.026 us; speedup vs baseline: 2.4643x; 2.4643x over previous
//
#include <hip/hip_runtime.h>
#include <hip/hip_bf16.h>

#define N_NODES 100000
#define N_EDGES 3200000
#define F_IN    128
#define H1F     64
#define H2F     32
#define NCLS    32

static __device__ __forceinline__ float b2f(__hip_bfloat16 v) {
    return __bfloat162float(v);
}
static __device__ __forceinline__ float ld(const void* p, size_t i, int isbf) {
    return isbf ? b2f(((const __hip_bfloat16*)p)[i]) : ((const float*)p)[i];
}

// flags[0] = edge_index is int64 ; flags[1] = float tensors are bf16

// ---------------- runtime dtype detection ----------------
__global__ void k_detect(const void* xbuf, const void* eibuf, int* flags) {
    if (threadIdx.x != 0 || blockIdx.x != 0) return;
    const unsigned* ew = (const unsigned*)eibuf;
    int z = 0;
    for (int k = 0; k < 256; ++k) z += (ew[2 * k + 1] == 0u) ? 1 : 0;
    flags[0] = (z >= 200) ? 1 : 0;
    const unsigned* xw = (const unsigned*)xbuf;
    int inr = 0;
    for (int k = 0; k < 256; ++k) {
        unsigned fb = (xw[k] & 0xFFFFu) << 16;
        float a = fabsf(__uint_as_float(fb));
        inr += (a >= 1e-4f && a <= 20.0f) ? 1 : 0;
    }
    flags[1] = (inr >= 160) ? 1 : 0;
}

// ---------------- degree ----------------
__global__ void k_zero_deg(int* __restrict__ deg) {
    int i = blockIdx.x * blockDim.x + threadIdx.x;
    if (i < N_NODES) deg[i] = 0;
}

__global__ void k_count_deg(const int* __restrict__ ei, int* __restrict__ deg,
                            const int* __restrict__ flags) {
    int e = blockIdx.x * blockDim.x + threadIdx.x;
    if (e >= N_EDGES) return;
    int d = flags[0] ? ei[2 * (N_EDGES + e)] : ei[N_EDGES + e];
    if ((unsigned)d < N_NODES) atomicAdd(&deg[d], 1);
}

__global__ void k_dinv(const int* __restrict__ deg, float* __restrict__ dinv) {
    int i = blockIdx.x * blockDim.x + threadIdx.x;
    if (i < N_NODES) dinv[i] = rsqrtf((float)deg[i] + 1.0f);  // +1 self-loop
}

// ---------------- exclusive scan: rowptr[0..N], single block 1024 thr ----------------
__global__ void k_scan(const int* __restrict__ deg, int* __restrict__ rowptr) {
    __shared__ int wsum[16];
    __shared__ int carry_s;
    int tid = threadIdx.x, lane = tid & 63, wave = tid >> 6;
    if (tid == 0) { carry_s = 0; rowptr[0] = 0; }
    __syncthreads();
    for (int base = 0; base < N_NODES; base += 1024) {
        int i = base + tid;
        int v = (i < N_NODES) ? deg[i] : 0;
        for (int off = 1; off < 64; off <<= 1) {       // inclusive wave scan
            int t = __shfl_up(v, off, 64);
            if (lane >= off) v += t;
        }
        if (lane == 63) wsum[wave] = v;
        __syncthreads();
        if (wave == 0 && lane < 16) {                  // scan of wave sums
            int w = wsum[lane];
            for (int off = 1; off < 16; off <<= 1) {
                int t = __shfl_up(w, off, 64);
                if (lane >= off) w += t;
            }
            wsum[lane] = w;
        }
        __syncthreads();
        int woff = (wave == 0) ? 0 : wsum[wave - 1];
        int incl = v + woff + carry_s;
        if (i < N_NODES) rowptr[i + 1] = incl;
        __syncthreads();
        if (tid == 1023) carry_s = incl;               // chunk total carried
        __syncthreads();
    }
}

// ---------------- CSR fill ----------------
__global__ void k_fillinit(const int* __restrict__ rowptr, int* __restrict__ cursor) {
    int i = blockIdx.x * blockDim.x + threadIdx.x;
    if (i < N_NODES) cursor[i] = rowptr[i];
}

__global__ void k_fill(const int* __restrict__ ei, const int* __restrict__ flags,
                       int* __restrict__ cursor, int* __restrict__ csr) {
    int e = blockIdx.x * blockDim.x + threadIdx.x;
    if (e >= N_EDGES) return;
    int s, d;
    if (flags[0]) { s = ei[2 * e]; d = ei[2 * (N_EDGES + e)]; }
    else          { s = ei[e];     d = ei[N_EDGES + e];       }
    if ((unsigned)s >= N_NODES || (unsigned)d >= N_NODES) return;
    int pos = atomicAdd(&cursor[d], 1);
    csr[pos] = s;
}

// ---------------- GEMM1: h1 = x @ W1 ----------------
__global__ void k_gemm1(const void* __restrict__ x, const void* __restrict__ W1,
                        float* __restrict__ h1, const int* __restrict__ flags) {
    int wid  = (blockIdx.x * blockDim.x + threadIdx.x) >> 6;
    int lane = threadIdx.x & 63;
    if (wid >= N_NODES) return;
    size_t xoff = (size_t)wid * F_IN;
    float acc = 0.f;
    if (flags[1]) {
        const __hip_bfloat16* xr = (const __hip_bfloat16*)x + xoff;
        const __hip_bfloat16* w  = (const __hip_bfloat16*)W1;
#pragma unroll 8
        for (int k = 0; k < F_IN; ++k) acc += b2f(xr[k]) * b2f(w[k * H1F + lane]);
    } else {
        const float* xr = (const float*)x + xoff;
        const float* w  = (const float*)W1;
#pragma unroll 8
        for (int k = 0; k < F_IN; ++k) acc += xr[k] * w[k * H1F + lane];
    }
    h1[(size_t)wid * H1F + lane] = acc;
}

// ---------------- aggregation 1: CSR gather, wave/node, lane=feat(64) ----------------
__global__ void k_agg1(const float* __restrict__ h1, const float* __restrict__ dinv,
                       const int* __restrict__ rowptr, const int* __restrict__ csr,
                       float* __restrict__ agg1) {
    int n    = (blockIdx.x * blockDim.x + threadIdx.x) >> 6;
    int lane = threadIdx.x & 63;
    if (n >= N_NODES) return;
    int beg = rowptr[n], end = rowptr[n + 1];
    float dn  = dinv[n];
    float acc = dn * h1[(size_t)n * H1F + lane];       // self-loop term
    for (int e = beg; e < end; ++e) {
        int s = csr[e];                                 // broadcast load
        acc += dinv[s] * h1[(size_t)s * H1F + lane];   // coalesced 256B row
    }
    agg1[(size_t)n * H1F + lane] = dn * acc;
}

// ---------------- GEMM2: h2 = relu(agg1+b1) @ W2, half-wave/node ----------------
__global__ void k_gemm2(const float* __restrict__ agg1, const void* __restrict__ b1,
                        const void* __restrict__ W2, float* __restrict__ h2,
                        const int* __restrict__ flags) {
    int tid  = blockIdx.x * blockDim.x + threadIdx.x;
    int node = tid >> 5;
    int f    = threadIdx.x & 31;
    if (node >= N_NODES) return;
    const float* ar = agg1 + (size_t)node * H1F;
    float acc = 0.f;
    if (flags[1]) {
        const __hip_bfloat16* bb = (const __hip_bfloat16*)b1;
        const __hip_bfloat16* w  = (const __hip_bfloat16*)W2;
#pragma unroll 8
        for (int k = 0; k < H1F; ++k)
            acc += fmaxf(ar[k] + b2f(bb[k]), 0.f) * b2f(w[k * H2F + f]);
    } else {
        const float* bb = (const float*)b1;
        const float* w  = (const float*)W2;
#pragma unroll 8
        for (int k = 0; k < H1F; ++k)
            acc += fmaxf(ar[k] + bb[k], 0.f) * w[k * H2F + f];
    }
    h2[(size_t)node * H2F + f] = acc;
}

// ---------------- aggregation 2: CSR gather, half-wave/node (32 feats) ----------------
__global__ void k_agg2(const float* __restrict__ h2, const float* __restrict__ dinv,
                       const int* __restrict__ rowptr, const int* __restrict__ csr,
                       float* __restrict__ agg2) {
    int tid  = blockIdx.x * blockDim.x + threadIdx.x;
    int n    = tid >> 5;
    int f    = threadIdx.x & 31;
    if (n >= N_NODES) return;
    int beg = rowptr[n], end = rowptr[n + 1];
    float dn  = dinv[n];
    float acc = dn * h2[(size_t)n * H2F + f];
    for (int e = beg; e < end; ++e) {
        int s = csr[e];
        acc += dinv[s] * h2[(size_t)s * H2F + f];
    }
    agg2[(size_t)n * H2F + f] = dn * acc;
}

// ---------------- final: out = relu((agg2+b2) @ Wf + bf) @ Wo + bo ----------------
__global__ void GCN_51737176048479_kernel(const float* __restrict__ agg2,
                                          const void* __restrict__ b2v,
                                          const void* __restrict__ Wf,
                                          const void* __restrict__ bfv,
                                          const void* __restrict__ Wo,
                                          const void* __restrict__ bo,
                                          void* __restrict__ out,
                                          const int* __restrict__ flags) {
    int tid  = blockIdx.x * blockDim.x + threadIdx.x;
    int node = tid >> 5;
    int f    = threadIdx.x & 31;
    if (node >= N_NODES) return;
    int isbf = flags[1];
    const float* ar = agg2 + (size_t)node * H2F;
    float acc1 = 0.f;
#pragma unroll
    for (int k = 0; k < H2F; ++k)
        acc1 += (ar[k] + ld(b2v, k, isbf)) * ld(Wf, (size_t)k * H2F + f, isbf);
    float u = fmaxf(acc1 + ld(bfv, f, isbf), 0.f);
    float acc2 = 0.f;
#pragma unroll
    for (int k = 0; k < H2F; ++k) {
        float uk = __shfl(u, k, 32);
        acc2 += uk * ld(Wo, (size_t)k * NCLS + f, isbf);
    }
    float r = acc2 + ld(bo, f, isbf);
    size_t oi = (size_t)node * NCLS + f;
    if (isbf) ((__hip_bfloat16*)out)[oi] = __float2bfloat16(r);
    else      ((float*)out)[oi] = r;
}

extern "C" void kernel_launch(void* const* d_in, const int* in_sizes, int n_in,
                              void* d_out, int out_size, void* d_ws, size_t ws_size,
                              hipStream_t stream) {
    const void* x  = d_in[0];
    const int*  ei = (const int*)d_in[1];
    const void* W1 = d_in[2];
    const void* b1 = d_in[3];
    const void* W2 = d_in[4];
    const void* b2 = d_in[5];
    const void* Wf = d_in[6];
    const void* bf = d_in[7];
    const void* Wo = d_in[8];
    const void* bo = d_in[9];

    // workspace layout (bytes), peak ~67.6 MB:
    //  deg @0 (400K) | rowptr @0.5M (400K+4) | cursor @1.0M (400K) | dinv @1.5M
    //  flags @1.9M | csr @2M (12.8M) | bufA @16M (25.6M: h1, then h2)
    //  bufB @42M (25.6M: agg1, then agg2)
    char* ws = (char*)d_ws;
    int*   deg    = (int*)  (ws + 0);
    int*   rowptr = (int*)  (ws + (512u  << 10));
    int*   cursor = (int*)  (ws + (1024u << 10));
    float* dinv   = (float*)(ws + (1536u << 10));
    int*   flags  = (int*)  (ws + (1945u << 10));
    int*   csr    = (int*)  (ws + (2u    << 20));
    float* h1     = (float*)(ws + (16u   << 20));
    float* agg1   = (float*)(ws + (42u   << 20));
    float* h2     = h1;     // bufA reuse
    float* agg2   = agg1;   // bufB reuse

    const int B = 256;

    k_detect<<<1, 64, 0, stream>>>(x, ei, flags);
    k_zero_deg<<<(N_NODES + B - 1) / B, B, 0, stream>>>(deg);
    k_count_deg<<<(N_EDGES + B - 1) / B, B, 0, stream>>>(ei, deg, flags);
    k_dinv<<<(N_NODES + B - 1) / B, B, 0, stream>>>(deg, dinv);
    k_scan<<<1, 1024, 0, stream>>>(deg, rowptr);
    k_fillinit<<<(N_NODES + B - 1) / B, B, 0, stream>>>(rowptr, cursor);
    k_fill<<<(N_EDGES + B - 1) / B, B, 0, stream>>>(ei, flags, cursor, csr);

    // layer 1
    k_gemm1<<<(N_NODES * 64 + B - 1) / B, B, 0, stream>>>(x, W1, h1, flags);
    k_agg1 <<<(N_NODES * 64 + B - 1) / B, B, 0, stream>>>(h1, dinv, rowptr, csr, agg1);

    // layer 2
    k_gemm2<<<(N_NODES * 32 + B - 1) / B, B, 0, stream>>>(agg1, b1, W2, h2, flags);
    k_agg2 <<<(N_NODES * 32 + B - 1) / B, B, 0, stream>>>(h2, dinv, rowptr, csr, agg2);

    // final MLP
    GCN_51737176048479_kernel<<<(N_NODES * 32 + B - 1) / B, B, 0, stream>>>(
        agg2, b2, Wf, bf, Wo, bo, d_out, flags);
}

// Round 7
// 786.981 us; speedup vs baseline: 4.1428x; 1.6811x over previous
//
#include <hip/hip_runtime.h>
#include <hip/hip_bf16.h>

#define N_NODES 100000
#define N_EDGES 3200000
#define F_IN    128
#define H1F     64
#define H2F     32
#define NCLS    32
#define SCAN_BLOCK 1024
#define SCAN_CHUNKS ((N_NODES + SCAN_BLOCK - 1) / SCAN_BLOCK)   // 98

static __device__ __forceinline__ float b2f(__hip_bfloat16 v) {
    return __bfloat162float(v);
}
static __device__ __forceinline__ float ld(const void* p, size_t i, int isbf) {
    return isbf ? b2f(((const __hip_bfloat16*)p)[i]) : ((const float*)p)[i];
}

// flags[0] = edge_index is int64 ; flags[1] = float tensors are bf16

__global__ void k_detect(const void* xbuf, const void* eibuf, int* flags) {
    if (threadIdx.x != 0 || blockIdx.x != 0) return;
    const unsigned* ew = (const unsigned*)eibuf;
    int z = 0;
    for (int k = 0; k < 256; ++k) z += (ew[2 * k + 1] == 0u) ? 1 : 0;
    flags[0] = (z >= 200) ? 1 : 0;
    const unsigned* xw = (const unsigned*)xbuf;
    int inr = 0;
    for (int k = 0; k < 256; ++k) {
        unsigned fb = (xw[k] & 0xFFFFu) << 16;
        float a = fabsf(__uint_as_float(fb));
        inr += (a >= 1e-4f && a <= 20.0f) ? 1 : 0;
    }
    flags[1] = (inr >= 160) ? 1 : 0;
}

__global__ void k_zero_deg(int* __restrict__ deg) {
    int i = blockIdx.x * blockDim.x + threadIdx.x;
    if (i < N_NODES) deg[i] = 0;
}

// histogram + per-edge rank (aux) in ONE pass; 4 edges/thread, int4 loads
__global__ void k_count(const int* __restrict__ ei, int* __restrict__ deg,
                        int* __restrict__ aux, const int* __restrict__ flags) {
    int t = blockIdx.x * blockDim.x + threadIdx.x;
    int e0 = t * 4;
    if (e0 >= N_EDGES) return;
    int d[4];
    if (flags[0]) {
        const int4* p = (const int4*)(ei + 2 * (size_t)(N_EDGES + e0));
        int4 a = p[0], b = p[1];
        d[0] = a.x; d[1] = a.z; d[2] = b.x; d[3] = b.z;
    } else {
        int4 a = *(const int4*)(ei + (size_t)N_EDGES + e0);
        d[0] = a.x; d[1] = a.y; d[2] = a.z; d[3] = a.w;
    }
    int p0 = ((unsigned)d[0] < N_NODES) ? atomicAdd(&deg[d[0]], 1) : 0;
    int p1 = ((unsigned)d[1] < N_NODES) ? atomicAdd(&deg[d[1]], 1) : 0;
    int p2 = ((unsigned)d[2] < N_NODES) ? atomicAdd(&deg[d[2]], 1) : 0;
    int p3 = ((unsigned)d[3] < N_NODES) ? atomicAdd(&deg[d[3]], 1) : 0;
    *(int4*)(aux + e0) = make_int4(p0, p1, p2, p3);
}

__global__ void k_dinv(const int* __restrict__ deg, float* __restrict__ dinv) {
    int i = blockIdx.x * blockDim.x + threadIdx.x;
    if (i < N_NODES) dinv[i] = rsqrtf((float)deg[i] + 1.0f);  // +1 self-loop
}

// ---------- 3-phase exclusive scan of deg -> rowptr ----------
__global__ void k_scanA(const int* __restrict__ deg, int* __restrict__ partial) {
    __shared__ int red[16];
    int b = blockIdx.x, t = threadIdx.x;
    int i = b * SCAN_BLOCK + t;
    int v = (i < N_NODES) ? deg[i] : 0;
    for (int off = 32; off; off >>= 1) v += __shfl_down(v, off, 64);
    if ((t & 63) == 0) red[t >> 6] = v;
    __syncthreads();
    if (t == 0) {
        int s = 0;
        for (int k = 0; k < 16; ++k) s += red[k];
        partial[b] = s;
    }
}

__global__ void k_scanB(const int* __restrict__ partial, int* __restrict__ chunkoff) {
    if (threadIdx.x != 0 || blockIdx.x != 0) return;
    int run = 0;
    for (int b = 0; b < SCAN_CHUNKS; ++b) { chunkoff[b] = run; run += partial[b]; }
}

__global__ void k_scanC(const int* __restrict__ deg, const int* __restrict__ chunkoff,
                        int* __restrict__ rowptr) {
    __shared__ int wsum[16];
    int b = blockIdx.x, t = threadIdx.x, lane = t & 63, w = t >> 6;
    int i = b * SCAN_BLOCK + t;
    int v = (i < N_NODES) ? deg[i] : 0;
    for (int off = 1; off < 64; off <<= 1) {
        int u = __shfl_up(v, off, 64);
        if (lane >= off) v += u;
    }
    if (lane == 63) wsum[w] = v;
    __syncthreads();
    if (t == 0) {
        int run = 0;
        for (int k = 0; k < 16; ++k) { int s = wsum[k]; wsum[k] = run; run += s; }
    }
    __syncthreads();
    int incl = v + wsum[w] + chunkoff[b];
    if (i < N_NODES) rowptr[i + 1] = incl;
    if (b == 0 && t == 0) rowptr[0] = 0;
}

// atomic-free CSR fill using precomputed ranks
__global__ void k_scatter(const int* __restrict__ ei, const int* __restrict__ aux,
                          const int* __restrict__ rowptr, int* __restrict__ csr,
                          const int* __restrict__ flags) {
    int t = blockIdx.x * blockDim.x + threadIdx.x;
    int e0 = t * 4;
    if (e0 >= N_EDGES) return;
    int s[4], d[4];
    if (flags[0]) {
        const int4* ps = (const int4*)(ei + 2 * (size_t)e0);
        int4 a = ps[0], b = ps[1];
        s[0] = a.x; s[1] = a.z; s[2] = b.x; s[3] = b.z;
        const int4* pd = (const int4*)(ei + 2 * (size_t)(N_EDGES + e0));
        int4 c = pd[0], g = pd[1];
        d[0] = c.x; d[1] = c.z; d[2] = g.x; d[3] = g.z;
    } else {
        int4 a = *(const int4*)(ei + (size_t)e0);
        s[0] = a.x; s[1] = a.y; s[2] = a.z; s[3] = a.w;
        int4 c = *(const int4*)(ei + (size_t)N_EDGES + e0);
        d[0] = c.x; d[1] = c.y; d[2] = c.z; d[3] = c.w;
    }
    int4 av = *(const int4*)(aux + e0);
    int a4[4] = { av.x, av.y, av.z, av.w };
#pragma unroll
    for (int j = 0; j < 4; ++j) {
        if ((unsigned)s[j] < N_NODES && (unsigned)d[j] < N_NODES)
            csr[rowptr[d[j]] + a4[j]] = s[j];
    }
}

// ---------------- GEMM1: h1 = x @ W1 ; x row via 1 vec load + shfl bcast ----------------
__global__ void k_gemm1(const void* __restrict__ x, const void* __restrict__ W1,
                        float* __restrict__ h1, const int* __restrict__ flags) {
    int gid  = blockIdx.x * blockDim.x + threadIdx.x;
    int n    = gid >> 6;
    int lane = threadIdx.x & 63;
    if (n >= N_NODES) return;
    float acc = 0.f;
    if (flags[1]) {
        const unsigned* xr = (const unsigned*)x + (size_t)n * (F_IN / 2);
        const __hip_bfloat16* w = (const __hip_bfloat16*)W1;
        unsigned myw = xr[lane];                       // 2 bf16 elems per lane
#pragma unroll 16
        for (int k = 0; k < 64; ++k) {
            unsigned wd = __shfl(myw, k, 64);
            float x0 = __uint_as_float(wd << 16);            // elem 2k
            float x1 = __uint_as_float(wd & 0xFFFF0000u);    // elem 2k+1
            acc += x0 * b2f(w[(2 * k) * H1F + lane]);
            acc += x1 * b2f(w[(2 * k + 1) * H1F + lane]);
        }
    } else {
        const float2* xr = (const float2*)((const float*)x + (size_t)n * F_IN);
        const float* w = (const float*)W1;
        float2 my = xr[lane];
#pragma unroll 16
        for (int k = 0; k < 64; ++k) {
            float x0 = __shfl(my.x, k, 64);
            float x1 = __shfl(my.y, k, 64);
            acc += x0 * w[(2 * k) * H1F + lane];
            acc += x1 * w[(2 * k + 1) * H1F + lane];
        }
    }
    h1[(size_t)n * H1F + lane] = acc;
}

// ---------------- fused agg1 + bias/ReLU + GEMM2 -> h2 ; wave per node ----------------
__global__ void k_agg1gemm2(const float* __restrict__ h1, const float* __restrict__ dinv,
                            const int* __restrict__ rowptr, const int* __restrict__ csr,
                            const void* __restrict__ b1, const void* __restrict__ W2,
                            float* __restrict__ h2, const int* __restrict__ flags) {
    int n    = (blockIdx.x * blockDim.x + threadIdx.x) >> 6;
    int lane = threadIdx.x & 63;
    if (n >= N_NODES) return;
    int beg = rowptr[n], end = rowptr[n + 1];
    float dn  = dinv[n];
    float acc = dn * h1[(size_t)n * H1F + lane];        // self-loop
    int e = beg;
    for (; e + 1 < end; e += 2) {                       // 2-deep MLP
        int s0 = csr[e], s1 = csr[e + 1];
        float w0 = dinv[s0], w1 = dinv[s1];
        acc += w0 * h1[(size_t)s0 * H1F + lane] + w1 * h1[(size_t)s1 * H1F + lane];
    }
    if (e < end) { int s = csr[e]; acc += dinv[s] * h1[(size_t)s * H1F + lane]; }
    acc *= dn;                                          // agg1[n][lane]
    // v = relu(agg1 + b1)
    int isbf = flags[1];
    float bv = isbf ? b2f(((const __hip_bfloat16*)b1)[lane]) : ((const float*)b1)[lane];
    float v  = fmaxf(acc + bv, 0.f);
    // h2[f] = sum_k v_k * W2[k][f] ; lane = f + 32*h, k-range split by h
    int f = lane & 31, h = lane >> 5;
    float part = 0.f;
    if (isbf) {
        const __hip_bfloat16* w = (const __hip_bfloat16*)W2;
#pragma unroll
        for (int j = 0; j < 32; ++j) {
            int k = h * 32 + j;
            part += __shfl(v, k, 64) * b2f(w[k * H2F + f]);
        }
    } else {
        const float* w = (const float*)W2;
#pragma unroll
        for (int j = 0; j < 32; ++j) {
            int k = h * 32 + j;
            part += __shfl(v, k, 64) * w[k * H2F + f];
        }
    }
    part += __shfl(part, lane ^ 32, 64);                // combine halves
    if (h == 0) h2[(size_t)n * H2F + f] = part;
}

// ---------------- fused agg2 + final MLP -> out ; half-wave per node ----------------
__global__ void GCN_51737176048479_kernel(const float* __restrict__ h2,
                                          const float* __restrict__ dinv,
                                          const int* __restrict__ rowptr,
                                          const int* __restrict__ csr,
                                          const void* __restrict__ b2v,
                                          const void* __restrict__ Wf,
                                          const void* __restrict__ bfv,
                                          const void* __restrict__ Wo,
                                          const void* __restrict__ bov,
                                          void* __restrict__ out,
                                          const int* __restrict__ flags) {
    int tid = blockIdx.x * blockDim.x + threadIdx.x;
    int n   = tid >> 5;
    int f   = threadIdx.x & 31;
    if (n >= N_NODES) return;
    int isbf = flags[1];
    int beg = rowptr[n], end = rowptr[n + 1];
    float dn = dinv[n];
    float ar = dn * h2[(size_t)n * H2F + f];
    int e = beg;
    for (; e + 1 < end; e += 2) {
        int s0 = csr[e], s1 = csr[e + 1];
        ar += dinv[s0] * h2[(size_t)s0 * H2F + f] + dinv[s1] * h2[(size_t)s1 * H2F + f];
    }
    if (e < end) { int s = csr[e]; ar += dinv[s] * h2[(size_t)s * H2F + f]; }
    ar = ar * dn + ld(b2v, f, isbf);                    // conv2 out (no relu)
    float acc1 = 0.f;
#pragma unroll
    for (int k = 0; k < H2F; ++k)
        acc1 += __shfl(ar, k, 32) * ld(Wf, (size_t)k * H2F + f, isbf);
    float u = fmaxf(acc1 + ld(bfv, f, isbf), 0.f);
    float acc2 = 0.f;
#pragma unroll
    for (int k = 0; k < H2F; ++k)
        acc2 += __shfl(u, k, 32) * ld(Wo, (size_t)k * NCLS + f, isbf);
    float r = acc2 + ld(bov, f, isbf);
    size_t oi = (size_t)n * NCLS + f;
    if (isbf) ((__hip_bfloat16*)out)[oi] = __float2bfloat16(r);
    else      ((float*)out)[oi] = r;
}

extern "C" void kernel_launch(void* const* d_in, const int* in_sizes, int n_in,
                              void* d_out, int out_size, void* d_ws, size_t ws_size,
                              hipStream_t stream) {
    const void* x  = d_in[0];
    const int*  ei = (const int*)d_in[1];
    const void* W1 = d_in[2];
    const void* b1 = d_in[3];
    const void* W2 = d_in[4];
    const void* b2 = d_in[5];
    const void* Wf = d_in[6];
    const void* bf = d_in[7];
    const void* Wo = d_in[8];
    const void* bo = d_in[9];

    // workspace (peak ~66.8 MB):
    //  deg @0 | rowptr @512K | dinv @1M | flags @1.4M | partial @1.41M | chunkoff @1.42M
    //  aux @2M (12.8M, dead after k_scatter) | csr @15M (12.8M)
    //  h1 @28M (25.6M, overlays dead aux region start)  | h2 @54M (12.8M)
    char* ws = (char*)d_ws;
    int*   deg      = (int*)  (ws + 0);
    int*   rowptr   = (int*)  (ws + (512u  << 10));
    float* dinv     = (float*)(ws + (1024u << 10));
    int*   flags    = (int*)  (ws + (1434u << 10));
    int*   partial  = (int*)  (ws + (1444u << 10));
    int*   chunkoff = (int*)  (ws + (1454u << 10));
    int*   aux      = (int*)  (ws + (2u  << 20));
    int*   csr      = (int*)  (ws + (15u << 20));
    float* h1       = (float*)(ws + (28u << 20));   // overlays aux (dead by then)
    float* h2       = (float*)(ws + (54u << 20));

    const int B = 256;

    k_detect<<<1, 64, 0, stream>>>(x, ei, flags);
    k_zero_deg<<<(N_NODES + B - 1) / B, B, 0, stream>>>(deg);
    k_count<<<(N_EDGES / 4 + B - 1) / B, B, 0, stream>>>(ei, deg, aux, flags);
    k_dinv<<<(N_NODES + B - 1) / B, B, 0, stream>>>(deg, dinv);
    k_scanA<<<SCAN_CHUNKS, SCAN_BLOCK, 0, stream>>>(deg, partial);
    k_scanB<<<1, 64, 0, stream>>>(partial, chunkoff);
    k_scanC<<<SCAN_CHUNKS, SCAN_BLOCK, 0, stream>>>(deg, chunkoff, rowptr);
    k_scatter<<<(N_EDGES / 4 + B - 1) / B, B, 0, stream>>>(ei, aux, rowptr, csr, flags);

    k_gemm1<<<(N_NODES * 64 + B - 1) / B, B, 0, stream>>>(x, W1, h1, flags);
    k_agg1gemm2<<<(N_NODES * 64 + B - 1) / B, B, 0, stream>>>(h1, dinv, rowptr, csr,
                                                              b1, W2, h2, flags);
    GCN_51737176048479_kernel<<<(N_NODES * 32 + B - 1) / B, B, 0, stream>>>(
        h2, dinv, rowptr, csr, b2, Wf, bf, Wo, bo, d_out, flags);
}

// Round 8
// 664.882 us; speedup vs baseline: 4.9036x; 1.1836x over previous
//
#include <hip/hip_runtime.h>
#include <hip/hip_bf16.h>

#define N_NODES 100000
#define N_EDGES 3200000
#define F_IN    128
#define H1F     64
#define H2F     32
#define NCLS    32
#define SCAN_BLOCK 1024
#define SCAN_CHUNKS ((N_NODES + SCAN_BLOCK - 1) / SCAN_BLOCK)   // 98

static __device__ __forceinline__ float b2f(__hip_bfloat16 v) {
    return __bfloat162float(v);
}
static __device__ __forceinline__ float us2f(unsigned short u) {
    return __uint_as_float(((unsigned)u) << 16);
}
static __device__ __forceinline__ unsigned short f2us(float f) {
    __hip_bfloat16 h = __float2bfloat16(f);
    return *(unsigned short*)&h;
}
static __device__ __forceinline__ float ld(const void* p, size_t i, int isbf) {
    return isbf ? b2f(((const __hip_bfloat16*)p)[i]) : ((const float*)p)[i];
}

// flags[0] = edge_index is int64 ; flags[1] = float tensors are bf16

__global__ void k_detect(const void* xbuf, const void* eibuf, int* flags) {
    if (threadIdx.x != 0 || blockIdx.x != 0) return;
    const unsigned* ew = (const unsigned*)eibuf;
    int z = 0;
    for (int k = 0; k < 256; ++k) z += (ew[2 * k + 1] == 0u) ? 1 : 0;
    flags[0] = (z >= 200) ? 1 : 0;
    const unsigned* xw = (const unsigned*)xbuf;
    int inr = 0;
    for (int k = 0; k < 256; ++k) {
        unsigned fb = (xw[k] & 0xFFFFu) << 16;
        float a = fabsf(__uint_as_float(fb));
        inr += (a >= 1e-4f && a <= 20.0f) ? 1 : 0;
    }
    flags[1] = (inr >= 160) ? 1 : 0;
}

// histogram + per-edge rank (aux) in ONE pass; 4 edges/thread, int4 loads
__global__ void k_count(const int* __restrict__ ei, int* __restrict__ deg,
                        int* __restrict__ aux, const int* __restrict__ flags) {
    int t = blockIdx.x * blockDim.x + threadIdx.x;
    int e0 = t * 4;
    if (e0 >= N_EDGES) return;
    int d[4];
    if (flags[0]) {
        const int4* p = (const int4*)(ei + 2 * (size_t)(N_EDGES + e0));
        int4 a = p[0], b = p[1];
        d[0] = a.x; d[1] = a.z; d[2] = b.x; d[3] = b.z;
    } else {
        int4 a = *(const int4*)(ei + (size_t)N_EDGES + e0);
        d[0] = a.x; d[1] = a.y; d[2] = a.z; d[3] = a.w;
    }
    int p0 = ((unsigned)d[0] < N_NODES) ? atomicAdd(&deg[d[0]], 1) : 0;
    int p1 = ((unsigned)d[1] < N_NODES) ? atomicAdd(&deg[d[1]], 1) : 0;
    int p2 = ((unsigned)d[2] < N_NODES) ? atomicAdd(&deg[d[2]], 1) : 0;
    int p3 = ((unsigned)d[3] < N_NODES) ? atomicAdd(&deg[d[3]], 1) : 0;
    *(int4*)(aux + e0) = make_int4(p0, p1, p2, p3);
}

__global__ void k_dinv(const int* __restrict__ deg, float* __restrict__ dinv) {
    int i = blockIdx.x * blockDim.x + threadIdx.x;
    if (i < N_NODES) dinv[i] = rsqrtf((float)deg[i] + 1.0f);  // +1 self-loop
}

// ---------- 3-phase exclusive scan of deg -> rowptr ----------
__global__ void k_scanA(const int* __restrict__ deg, int* __restrict__ partial) {
    __shared__ int red[16];
    int b = blockIdx.x, t = threadIdx.x;
    int i = b * SCAN_BLOCK + t;
    int v = (i < N_NODES) ? deg[i] : 0;
    for (int off = 32; off; off >>= 1) v += __shfl_down(v, off, 64);
    if ((t & 63) == 0) red[t >> 6] = v;
    __syncthreads();
    if (t == 0) {
        int s = 0;
        for (int k = 0; k < 16; ++k) s += red[k];
        partial[b] = s;
    }
}

__global__ void k_scanB(const int* __restrict__ partial, int* __restrict__ chunkoff) {
    if (threadIdx.x != 0 || blockIdx.x != 0) return;
    int run = 0;
    for (int b = 0; b < SCAN_CHUNKS; ++b) { chunkoff[b] = run; run += partial[b]; }
}

__global__ void k_scanC(const int* __restrict__ deg, const int* __restrict__ chunkoff,
                        int* __restrict__ rowptr) {
    __shared__ int wsum[16];
    int b = blockIdx.x, t = threadIdx.x, lane = t & 63, w = t >> 6;
    int i = b * SCAN_BLOCK + t;
    int v = (i < N_NODES) ? deg[i] : 0;
    for (int off = 1; off < 64; off <<= 1) {
        int u = __shfl_up(v, off, 64);
        if (lane >= off) v += u;
    }
    if (lane == 63) wsum[w] = v;
    __syncthreads();
    if (t == 0) {
        int run = 0;
        for (int k = 0; k < 16; ++k) { int s = wsum[k]; wsum[k] = run; run += s; }
    }
    __syncthreads();
    int incl = v + wsum[w] + chunkoff[b];
    if (i < N_NODES) rowptr[i + 1] = incl;
    if (b == 0 && t == 0) rowptr[0] = 0;
}

// atomic-free CSR fill using precomputed ranks
__global__ void k_scatter(const int* __restrict__ ei, const int* __restrict__ aux,
                          const int* __restrict__ rowptr, int* __restrict__ csr,
                          const int* __restrict__ flags) {
    int t = blockIdx.x * blockDim.x + threadIdx.x;
    int e0 = t * 4;
    if (e0 >= N_EDGES) return;
    int s[4], d[4];
    if (flags[0]) {
        const int4* ps = (const int4*)(ei + 2 * (size_t)e0);
        int4 a = ps[0], b = ps[1];
        s[0] = a.x; s[1] = a.z; s[2] = b.x; s[3] = b.z;
        const int4* pd = (const int4*)(ei + 2 * (size_t)(N_EDGES + e0));
        int4 c = pd[0], g = pd[1];
        d[0] = c.x; d[1] = c.z; d[2] = g.x; d[3] = g.z;
    } else {
        int4 a = *(const int4*)(ei + (size_t)e0);
        s[0] = a.x; s[1] = a.y; s[2] = a.z; s[3] = a.w;
        int4 c = *(const int4*)(ei + (size_t)N_EDGES + e0);
        d[0] = c.x; d[1] = c.y; d[2] = c.z; d[3] = c.w;
    }
    int4 av = *(const int4*)(aux + e0);
    int a4[4] = { av.x, av.y, av.z, av.w };
#pragma unroll
    for (int j = 0; j < 4; ++j) {
        if ((unsigned)s[j] < N_NODES && (unsigned)d[j] < N_NODES)
            csr[rowptr[d[j]] + a4[j]] = s[j];
    }
}

// ---------------- GEMM1: h1(bf16) = x @ W1 ; x row via vec load + shfl bcast ----------------
__global__ void k_gemm1(const void* __restrict__ x, const void* __restrict__ W1,
                        unsigned short* __restrict__ h1, const int* __restrict__ flags) {
    int gid  = blockIdx.x * blockDim.x + threadIdx.x;
    int n    = gid >> 6;
    int lane = threadIdx.x & 63;
    if (n >= N_NODES) return;
    float acc = 0.f;
    if (flags[1]) {
        const unsigned* xr = (const unsigned*)x + (size_t)n * (F_IN / 2);
        const __hip_bfloat16* w = (const __hip_bfloat16*)W1;
        unsigned myw = xr[lane];                       // 2 bf16 elems per lane
#pragma unroll 16
        for (int k = 0; k < 64; ++k) {
            unsigned wd = __shfl(myw, k, 64);
            float x0 = __uint_as_float(wd << 16);            // elem 2k
            float x1 = __uint_as_float(wd & 0xFFFF0000u);    // elem 2k+1
            acc += x0 * b2f(w[(2 * k) * H1F + lane]);
            acc += x1 * b2f(w[(2 * k + 1) * H1F + lane]);
        }
    } else {
        const float2* xr = (const float2*)((const float*)x + (size_t)n * F_IN);
        const float* w = (const float*)W1;
        float2 my = xr[lane];
#pragma unroll 16
        for (int k = 0; k < 64; ++k) {
            float x0 = __shfl(my.x, k, 64);
            float x1 = __shfl(my.y, k, 64);
            acc += x0 * w[(2 * k) * H1F + lane];
            acc += x1 * w[(2 * k + 1) * H1F + lane];
        }
    }
    h1[(size_t)n * H1F + lane] = f2us(acc);
}

// ---------------- fused agg1 + bias/ReLU + GEMM2 -> h2(bf16) ; wave per node ----------------
__global__ void k_agg1gemm2(const unsigned short* __restrict__ h1,
                            const float* __restrict__ dinv,
                            const int* __restrict__ rowptr, const int* __restrict__ csr,
                            const void* __restrict__ b1, const void* __restrict__ W2,
                            unsigned short* __restrict__ h2, const int* __restrict__ flags) {
    int n    = (blockIdx.x * blockDim.x + threadIdx.x) >> 6;
    int lane = threadIdx.x & 63;
    if (n >= N_NODES) return;
    int beg = rowptr[n], end = rowptr[n + 1];
    float dn  = dinv[n];
    float acc = dn * us2f(h1[(size_t)n * H1F + lane]);  // self-loop
    int e = beg;
    for (; e + 3 < end; e += 4) {                       // 4-deep MLP
        int s0 = csr[e], s1 = csr[e + 1], s2 = csr[e + 2], s3 = csr[e + 3];
        float w0 = dinv[s0], w1 = dinv[s1], w2 = dinv[s2], w3 = dinv[s3];
        unsigned short v0 = h1[(size_t)s0 * H1F + lane];
        unsigned short v1 = h1[(size_t)s1 * H1F + lane];
        unsigned short v2 = h1[(size_t)s2 * H1F + lane];
        unsigned short v3 = h1[(size_t)s3 * H1F + lane];
        acc += w0 * us2f(v0) + w1 * us2f(v1) + w2 * us2f(v2) + w3 * us2f(v3);
    }
    for (; e < end; ++e) {
        int s = csr[e];
        acc += dinv[s] * us2f(h1[(size_t)s * H1F + lane]);
    }
    acc *= dn;                                          // agg1[n][lane]
    int isbf = flags[1];
    float bv = isbf ? b2f(((const __hip_bfloat16*)b1)[lane]) : ((const float*)b1)[lane];
    float v  = fmaxf(acc + bv, 0.f);                    // relu(agg1 + b1)
    // h2[f] = sum_k v_k * W2[k][f] ; lane = f + 32*h, k-range split by h
    int f = lane & 31, h = lane >> 5;
    float part = 0.f;
    if (isbf) {
        const __hip_bfloat16* w = (const __hip_bfloat16*)W2;
#pragma unroll
        for (int j = 0; j < 32; ++j) {
            int k = h * 32 + j;
            part += __shfl(v, k, 64) * b2f(w[k * H2F + f]);
        }
    } else {
        const float* w = (const float*)W2;
#pragma unroll
        for (int j = 0; j < 32; ++j) {
            int k = h * 32 + j;
            part += __shfl(v, k, 64) * w[k * H2F + f];
        }
    }
    part += __shfl(part, lane ^ 32, 64);                // combine halves
    if (h == 0) h2[(size_t)n * H2F + f] = f2us(part);
}

// ---------------- fused agg2 + final MLP -> out ; half-wave per node ----------------
__global__ void GCN_51737176048479_kernel(const unsigned short* __restrict__ h2,
                                          const float* __restrict__ dinv,
                                          const int* __restrict__ rowptr,
                                          const int* __restrict__ csr,
                                          const void* __restrict__ b2v,
                                          const void* __restrict__ Wf,
                                          const void* __restrict__ bfv,
                                          const void* __restrict__ Wo,
                                          const void* __restrict__ bov,
                                          void* __restrict__ out,
                                          const int* __restrict__ flags) {
    int tid = blockIdx.x * blockDim.x + threadIdx.x;
    int n   = tid >> 5;
    int f   = threadIdx.x & 31;
    if (n >= N_NODES) return;
    int isbf = flags[1];
    int beg = rowptr[n], end = rowptr[n + 1];
    float dn = dinv[n];
    float ar = dn * us2f(h2[(size_t)n * H2F + f]);
    int e = beg;
    for (; e + 3 < end; e += 4) {
        int s0 = csr[e], s1 = csr[e + 1], s2 = csr[e + 2], s3 = csr[e + 3];
        float w0 = dinv[s0], w1 = dinv[s1], w2 = dinv[s2], w3 = dinv[s3];
        unsigned short v0 = h2[(size_t)s0 * H2F + f];
        unsigned short v1 = h2[(size_t)s1 * H2F + f];
        unsigned short v2 = h2[(size_t)s2 * H2F + f];
        unsigned short v3 = h2[(size_t)s3 * H2F + f];
        ar += w0 * us2f(v0) + w1 * us2f(v1) + w2 * us2f(v2) + w3 * us2f(v3);
    }
    for (; e < end; ++e) {
        int s = csr[e];
        ar += dinv[s] * us2f(h2[(size_t)s * H2F + f]);
    }
    ar = ar * dn + ld(b2v, f, isbf);                    // conv2 out (no relu)
    float acc1 = 0.f;
#pragma unroll
    for (int k = 0; k < H2F; ++k)
        acc1 += __shfl(ar, k, 32) * ld(Wf, (size_t)k * H2F + f, isbf);
    float u = fmaxf(acc1 + ld(bfv, f, isbf), 0.f);
    float acc2 = 0.f;
#pragma unroll
    for (int k = 0; k < H2F; ++k)
        acc2 += __shfl(u, k, 32) * ld(Wo, (size_t)k * NCLS + f, isbf);
    float r = acc2 + ld(bov, f, isbf);
    size_t oi = (size_t)n * NCLS + f;
    if (isbf) ((__hip_bfloat16*)out)[oi] = __float2bfloat16(r);
    else      ((float*)out)[oi] = r;
}

extern "C" void kernel_launch(void* const* d_in, const int* in_sizes, int n_in,
                              void* d_out, int out_size, void* d_ws, size_t ws_size,
                              hipStream_t stream) {
    const void* x  = d_in[0];
    const int*  ei = (const int*)d_in[1];
    const void* W1 = d_in[2];
    const void* b1 = d_in[3];
    const void* W2 = d_in[4];
    const void* b2 = d_in[5];
    const void* Wf = d_in[6];
    const void* bf = d_in[7];
    const void* Wo = d_in[8];
    const void* bo = d_in[9];

    // workspace (peak ~48 MB):
    //  deg @0 | rowptr @512K | dinv @1M | flags @1.4M | partial @1.41M | chunkoff @1.42M
    //  aux @2M (12.8M) | csr @15M (12.8M) | h1 @28M (12.8M bf16) | h2 @41M (6.4M bf16)
    char* ws = (char*)d_ws;
    int*            deg      = (int*)  (ws + 0);
    int*            rowptr   = (int*)  (ws + (512u  << 10));
    float*          dinv     = (float*)(ws + (1024u << 10));
    int*            flags    = (int*)  (ws + (1434u << 10));
    int*            partial  = (int*)  (ws + (1444u << 10));
    int*            chunkoff = (int*)  (ws + (1454u << 10));
    int*            aux      = (int*)  (ws + (2u  << 20));
    int*            csr      = (int*)  (ws + (15u << 20));
    unsigned short* h1       = (unsigned short*)(ws + (28u << 20));
    unsigned short* h2       = (unsigned short*)(ws + (41u << 20));

    const int B = 256;

    k_detect<<<1, 64, 0, stream>>>(x, ei, flags);
    hipMemsetAsync(deg, 0, N_NODES * sizeof(int), stream);
    k_count<<<(N_EDGES / 4 + B - 1) / B, B, 0, stream>>>(ei, deg, aux, flags);
    k_dinv<<<(N_NODES + B - 1) / B, B, 0, stream>>>(deg, dinv);
    k_scanA<<<SCAN_CHUNKS, SCAN_BLOCK, 0, stream>>>(deg, partial);
    k_scanB<<<1, 64, 0, stream>>>(partial, chunkoff);
    k_scanC<<<SCAN_CHUNKS, SCAN_BLOCK, 0, stream>>>(deg, chunkoff, rowptr);
    k_scatter<<<(N_EDGES / 4 + B - 1) / B, B, 0, stream>>>(ei, aux, rowptr, csr, flags);

    k_gemm1<<<(N_NODES * 64 + B - 1) / B, B, 0, stream>>>(x, W1, h1, flags);
    k_agg1gemm2<<<(N_NODES * 64 + B - 1) / B, B, 0, stream>>>(h1, dinv, rowptr, csr,
                                                              b1, W2, h2, flags);
    GCN_51737176048479_kernel<<<(N_NODES * 32 + B - 1) / B, B, 0, stream>>>(
        h2, dinv, rowptr, csr, b2, Wf, bf, Wo, bo, d_out, flags);
}